// Round 3
// baseline (255.881 us; speedup 1.0000x reference)
//
#include <hip/hip_runtime.h>
#include <math.h>

#define HH   1024
#define WW   1024
#define NIMG 32
#define BIGD (1<<20)

// d_ws layout: [0] double bce_sum, [8] u64 penalty_total, [16] u32 count,
//              [64 ..) maskT (4 MiB), then maskP (4 MiB)
#define MASK_BYTES (NIMG * HH * (WW / 8))          // 4,194,304
#define WS_NEEDED  (64 + 2 * (size_t)MASK_BYTES)

// ---------------------------------------------------------------------------
// Kernel 1: pure stream — BCE partial sums + 2-bit/elem mask bytes
// ---------------------------------------------------------------------------
__global__ __launch_bounds__(256) void dtl_stream(const float* __restrict__ pred,
                                                  const float* __restrict__ tgt,
                                                  unsigned char* __restrict__ maskT,
                                                  unsigned char* __restrict__ maskP,
                                                  double* __restrict__ acc) {
    const unsigned u = blockIdx.x * 256u + threadIdx.x;   // one 8-element group
    const float4* P = (const float4*)pred + 2u * (size_t)u;
    const float4* T = (const float4*)tgt  + 2u * (size_t)u;
    const float4 p0 = P[0], p1 = P[1];
    const float4 t0 = T[0], t1 = T[1];

    const float pv[8] = {p0.x, p0.y, p0.z, p0.w, p1.x, p1.y, p1.z, p1.w};
    const float tv[8] = {t0.x, t0.y, t0.z, t0.w, t1.x, t1.y, t1.z, t1.w};

    float bce = 0.f;
    unsigned tb = 0u, pb = 0u;
#pragma unroll
    for (int k = 0; k < 8; ++k) {
        const float p = pv[k], t = tv[k];
        bce += fmaxf(p, 0.f) - p * t + __logf(1.f + __expf(-fabsf(p)));
        tb |= ((unsigned)t) << k;                 // t ∈ {0.0f, 1.0f}
        pb |= (p > 0.f ? 1u : 0u) << k;           // sigmoid(p)>0.5 ⇔ p>0
    }
    maskT[u] = (unsigned char)tb;
    maskP[u] = (unsigned char)pb;

    // wave shuffle reduce (width 64), then tiny LDS hop, one f64 atomic/block
    float v = bce;
#pragma unroll
    for (int o = 32; o > 0; o >>= 1) v += __shfl_down(v, o);
    __shared__ float rf[4];
    if ((threadIdx.x & 63) == 0) rf[threadIdx.x >> 6] = v;
    __syncthreads();
    if (threadIdx.x == 0)
        atomicAdd(acc, (double)(rf[0] + rf[1] + rf[2] + rf[3]));
}

// ---------------------------------------------------------------------------
// Kernel 2: distance transform + border sums from bitmasks
// block = (image n, 32-col word group j); 512 threads = 32 cols x 16 chunks
// ---------------------------------------------------------------------------
__global__ __launch_bounds__(512) void dtl_dist(const unsigned* __restrict__ Tg,
                                                const unsigned* __restrict__ Pg,
                                                double* __restrict__ acc) {
    __shared__ unsigned Tw[HH];
    __shared__ unsigned Pw[HH];
    __shared__ int st_first[16][32];
    __shared__ int st_last[16][32];
    __shared__ unsigned rt[8], rc[8];

    const int tid  = threadIdx.x;
    const int n    = blockIdx.x >> 5;
    const int j    = blockIdx.x & 31;
    const int base = n * (HH * 32) + j;           // word index of (n, h=0, j)

    {   // gather this column of words (stride 32 words); 4 loads in flight
        const int h1 = tid, h2 = tid + 512;
        const unsigned a  = Tg[base + h1 * 32];
        const unsigned b  = Tg[base + h2 * 32];
        const unsigned c2 = Pg[base + h1 * 32];
        const unsigned d  = Pg[base + h2 * 32];
        Tw[h1] = a; Tw[h2] = b; Pw[h1] = c2; Pw[h2] = d;
    }
    __syncthreads();

    const int c  = tid & 31;                      // column within word
    const int q  = tid >> 5;                      // 64-row chunk
    const int h0 = q * 64;

    // compact column c, rows h0..h0+63 into u64 masks (b128 LDS reads)
    unsigned long long tw = 0ull, pw = 0ull;
#pragma unroll
    for (int g = 0; g < 16; ++g) {
        const uint4 a = *(const uint4*)&Tw[h0 + 4 * g];
        const uint4 b = *(const uint4*)&Pw[h0 + 4 * g];
        const unsigned tn = ((a.x >> c) & 1u) | (((a.y >> c) & 1u) << 1) |
                            (((a.z >> c) & 1u) << 2) | (((a.w >> c) & 1u) << 3);
        const unsigned pn = ((b.x >> c) & 1u) | (((b.y >> c) & 1u) << 1) |
                            (((b.z >> c) & 1u) << 2) | (((b.w >> c) & 1u) << 3);
        tw |= (unsigned long long)tn << (4 * g);
        pw |= (unsigned long long)pn << (4 * g);
    }

    const int first = tw ? __builtin_ctzll(tw) : -1;
    const int last  = tw ? (63 - __builtin_clzll(tw)) : -1;
    st_first[q][c] = first;
    st_last[q][c]  = last;
    __syncthreads();

    // cross-chunk carries
    int U = BIGD;                                 // dist from row h0-1 up to nearest target
    for (int k = q - 1; k >= 0; --k) {
        const int l2 = st_last[k][c];
        if (l2 >= 0) { U = (h0 - 1) - (k * 64 + l2); break; }
    }
    int nxt_below = BIGD;                         // first target row below this chunk
    for (int k = q + 1; k < 16; ++k) {
        const int fs = st_first[k][c];
        if (fs >= 0) { nxt_below = k * 64 + fs; break; }
    }

    int f   = U;                                  // fwd dist at row h0-1
    int nxt = (first >= 0) ? (h0 + first) : nxt_below;
    unsigned tot = 0u, cnt = 0u;

#pragma unroll 4
    for (int b = 0; b < 64; ++b) {
        const int h = h0 + b;
        const int t = (int)((tw >> b) & 1ull);
        f = t ? 0 : (f + 1);
        if (h > nxt) {                            // passed a target: next set bit >= b
            const unsigned long long m = tw & (~0ull << b);
            nxt = m ? (h0 + __builtin_ctzll(m)) : nxt_below;
        }
        int d = nxt - h;
        d = (f < d) ? f : d;
        d = (d < HH) ? d : HH;                    // cap (no-target columns)
        if (((pw >> b) & 1ull) && d > 0) { tot += (unsigned)d; cnt += 1u; }
    }

    // reduce tot/cnt: wave shuffles then one atomic pair per block
    unsigned vt = tot, vc = cnt;
#pragma unroll
    for (int o = 32; o > 0; o >>= 1) { vt += __shfl_down(vt, o); vc += __shfl_down(vc, o); }
    if ((tid & 63) == 0) { rt[tid >> 6] = vt; rc[tid >> 6] = vc; }
    __syncthreads();
    if (tid == 0) {
        unsigned st = 0, sc = 0;
#pragma unroll
        for (int i = 0; i < 8; ++i) { st += rt[i]; sc += rc[i]; }
        atomicAdd((unsigned long long*)(acc + 1), (unsigned long long)st);
        atomicAdd((unsigned*)(acc + 2), sc);
    }
}

// ---------------------------------------------------------------------------
// Fallback fused kernel (round-2 verified) — used only if ws_size is small
// ---------------------------------------------------------------------------
__global__ __launch_bounds__(512, 4) void dtl_fused(const float* __restrict__ pred,
                                                    const float* __restrict__ tgt,
                                                    double* __restrict__ acc) {
    __shared__ unsigned long long tb64[HH / 2];
    __shared__ unsigned long long pb64[HH / 2];
    __shared__ int st_first[16][32];
    __shared__ int st_last[16][32];
    __shared__ float    red_f[512];
    __shared__ unsigned red_t[512];
    __shared__ unsigned red_c[512];

    const int tid  = threadIdx.x;
    const int lane = tid & 63;
    const int wv   = tid >> 6;
    const int n    = blockIdx.x >> 5;
    const int wb   = (blockIdx.x & 31) * 32;

    const int hh = wv * 128 + (lane >> 5);
    const int w  = wb + (lane & 31);
    const float* Pp = pred + ((size_t)n * HH + hh) * WW + w;
    const float* Tp = tgt  + ((size_t)n * HH + hh) * WW + w;

    float bce = 0.f;
    const int widx = wv * 64;

#pragma unroll 1
    for (int i = 0; i < 64; i += 4) {
        const float p0 = Pp[0 * 2048], p1 = Pp[1 * 2048], p2 = Pp[2 * 2048], p3 = Pp[3 * 2048];
        const float t0 = Tp[0 * 2048], t1 = Tp[1 * 2048], t2 = Tp[2 * 2048], t3 = Tp[3 * 2048];
        Pp += 4 * 2048; Tp += 4 * 2048;

        bce += fmaxf(p0, 0.f) - p0 * t0 + __logf(1.f + __expf(-fabsf(p0)));
        bce += fmaxf(p1, 0.f) - p1 * t1 + __logf(1.f + __expf(-fabsf(p1)));
        bce += fmaxf(p2, 0.f) - p2 * t2 + __logf(1.f + __expf(-fabsf(p2)));
        bce += fmaxf(p3, 0.f) - p3 * t3 + __logf(1.f + __expf(-fabsf(p3)));

        const unsigned long long bt0 = __ballot(t0 != 0.f), bp0 = __ballot(p0 > 0.f);
        const unsigned long long bt1 = __ballot(t1 != 0.f), bp1 = __ballot(p1 > 0.f);
        const unsigned long long bt2 = __ballot(t2 != 0.f), bp2 = __ballot(p2 > 0.f);
        const unsigned long long bt3 = __ballot(t3 != 0.f), bp3 = __ballot(p3 > 0.f);
        if (lane == 0) {
            tb64[widx + i + 0] = bt0;  pb64[widx + i + 0] = bp0;
            tb64[widx + i + 1] = bt1;  pb64[widx + i + 1] = bp1;
            tb64[widx + i + 2] = bt2;  pb64[widx + i + 2] = bp2;
            tb64[widx + i + 3] = bt3;  pb64[widx + i + 3] = bp3;
        }
    }
    __syncthreads();

    const int c  = tid & 31;
    const int q  = tid >> 5;
    const int h0 = q * 64;

    unsigned long long tw = 0ull, pw = 0ull;
#pragma unroll 8
    for (int jj = 0; jj < 32; ++jj) {
        const unsigned long long wt = tb64[q * 32 + jj];
        const unsigned long long wp = pb64[q * 32 + jj];
        tw |= (((wt >> c) & 1ull) << (2 * jj)) | (((wt >> (c + 32)) & 1ull) << (2 * jj + 1));
        pw |= (((wp >> c) & 1ull) << (2 * jj)) | (((wp >> (c + 32)) & 1ull) << (2 * jj + 1));
    }
    const int first = tw ? __builtin_ctzll(tw) : -1;
    const int last  = tw ? (63 - __builtin_clzll(tw)) : -1;
    st_first[q][c] = first;
    st_last[q][c]  = last;
    __syncthreads();

    int U = BIGD;
    for (int k = q - 1; k >= 0; --k) {
        const int l2 = st_last[k][c];
        if (l2 >= 0) { U = (h0 - 1) - (k * 64 + l2); break; }
    }
    int nxt_below = BIGD;
    for (int k = q + 1; k < 16; ++k) {
        const int fs = st_first[k][c];
        if (fs >= 0) { nxt_below = k * 64 + fs; break; }
    }

    int f   = U;
    int nxt = (first >= 0) ? (h0 + first) : nxt_below;
    unsigned tot = 0u, cnt = 0u;

#pragma unroll 4
    for (int b = 0; b < 64; ++b) {
        const int h = h0 + b;
        const int t = (int)((tw >> b) & 1ull);
        f = t ? 0 : (f + 1);
        if (h > nxt) {
            const unsigned long long m = tw & (~0ull << b);
            nxt = m ? (h0 + __builtin_ctzll(m)) : nxt_below;
        }
        int d = nxt - h;
        d = (f < d) ? f : d;
        d = (d < HH) ? d : HH;
        if (((pw >> b) & 1ull) && d > 0) { tot += (unsigned)d; cnt += 1u; }
    }

    red_f[tid] = bce; red_t[tid] = tot; red_c[tid] = cnt;
    __syncthreads();
    for (int off = 256; off > 0; off >>= 1) {
        if (tid < off) {
            red_f[tid] += red_f[tid + off];
            red_t[tid] += red_t[tid + off];
            red_c[tid] += red_c[tid + off];
        }
        __syncthreads();
    }
    if (tid == 0) {
        atomicAdd(acc, (double)red_f[0]);
        atomicAdd((unsigned long long*)(acc + 1), (unsigned long long)red_t[0]);
        atomicAdd((unsigned*)(acc + 2), red_c[0]);
    }
}

__global__ void dtl_final(const double* __restrict__ acc, float* __restrict__ out) {
    const double bce = acc[0] / (double)((size_t)NIMG * HH * WW);
    const unsigned long long tot = ((const unsigned long long*)acc)[1];
    const unsigned cnt = ((const unsigned*)acc)[4];   // byte offset 16
    double border = 0.0;
    if (tot != 0ull) {
        const unsigned cc = (cnt > 1u) ? cnt : 1u;
        border = sqrt((double)tot / (double)cc);
    }
    out[0] = (float)(bce + border);
}

extern "C" void kernel_launch(void* const* d_in, const int* in_sizes, int n_in,
                              void* d_out, int out_size, void* d_ws, size_t ws_size,
                              hipStream_t stream) {
    const float* pred = (const float*)d_in[0];
    const float* tgt  = (const float*)d_in[1];
    float* out = (float*)d_out;

    hipMemsetAsync(d_ws, 0, 32, stream);   // zero accumulators (capturable)

    if (ws_size >= WS_NEEDED) {
        unsigned char* maskT = (unsigned char*)d_ws + 64;
        unsigned char* maskP = maskT + MASK_BYTES;

        const int nGroups = NIMG * HH * WW / 8;          // 4,194,304
        dtl_stream<<<nGroups / 256, 256, 0, stream>>>(pred, tgt, maskT, maskP,
                                                      (double*)d_ws);
        dtl_dist<<<NIMG * 32, 512, 0, stream>>>((const unsigned*)maskT,
                                                (const unsigned*)maskP,
                                                (double*)d_ws);
    } else {
        dtl_fused<<<NIMG * 32, 512, 0, stream>>>(pred, tgt, (double*)d_ws);
    }
    dtl_final<<<1, 1, 0, stream>>>((const double*)d_ws, out);
}

// Round 4
// 151.121 us; speedup vs baseline: 1.6932x; 1.6932x over previous
//
#include <hip/hip_runtime.h>
#include <math.h>

#define HH   1024
#define WW   1024
#define NIMG 32
#define NBLK (NIMG * (WW / 32))     // 1024 blocks: (image, 32-col strip)
#define NT   512
#define BIGD (1<<20)

// d_ws layout: double bceP[NBLK]; unsigned totP[NBLK]; unsigned cntP[NBLK]
//   bytes: 8192 + 4096 + 4096 = 16 KiB

__global__ __launch_bounds__(NT) void dtl_main(const float* __restrict__ pred,
                                               const float* __restrict__ tgt,
                                               double* __restrict__ bceP,
                                               unsigned* __restrict__ totP,
                                               unsigned* __restrict__ cntP) {
    // nibw[row>>6][ quad*8 + (row&7) ] : byte s of the u64 = nibble-pair for
    // row (row>>6)*64 + s*8 + (row&7), cols quad*4..quad*4+3  (T in bits0-3, P in bits4-7)
    __shared__ unsigned long long nibw[16][64];      // 8 KiB
    __shared__ int st_first[16][32];
    __shared__ int st_last[16][32];
    __shared__ float    red_f[NT];
    __shared__ unsigned red_t[NT];
    __shared__ unsigned red_c[NT];

    const int tid   = threadIdx.x;
    const int lane  = tid & 63;
    const int wv    = tid >> 6;                      // 0..7
    const int n     = blockIdx.x >> 5;               // image
    const int strip = blockIdx.x & 31;               // col base = strip*32

    // ---------------- Phase A: coalesced float4 stream -> BCE + LDS nibbles --
    const int rlow = lane & 7;                       // row offset within octet
    const int quad = lane >> 3;                      // col quad within strip (0..7)
    const size_t f4base = ((size_t)n * HH + (size_t)(wv * 128 + rlow)) * (WW / 4)
                        + (size_t)(strip * 8 + quad);
    const float4* Pp = (const float4*)pred + f4base;
    const float4* Tp = (const float4*)tgt  + f4base;

    float bce = 0.f;
#pragma unroll
    for (int g = 0; g < 2; ++g) {                    // two 64-row groups per wave
        unsigned long long nv = 0ull;
#pragma unroll
        for (int s = 0; s < 8; ++s) {                // 8 row-octets per group
            const int off = g * 16384 + s * 2048;    // (g*64 + s*8) rows * 256 f4/row
            const float4 p = Pp[off];
            const float4 t = Tp[off];

            bce += fmaxf(p.x, 0.f) - p.x * t.x + __logf(1.f + __expf(-fabsf(p.x)));
            bce += fmaxf(p.y, 0.f) - p.y * t.y + __logf(1.f + __expf(-fabsf(p.y)));
            bce += fmaxf(p.z, 0.f) - p.z * t.z + __logf(1.f + __expf(-fabsf(p.z)));
            bce += fmaxf(p.w, 0.f) - p.w * t.w + __logf(1.f + __expf(-fabsf(p.w)));

            const unsigned tn = (unsigned)t.x | ((unsigned)t.y << 1) |
                                ((unsigned)t.z << 2) | ((unsigned)t.w << 3);
            const unsigned pn = (p.x > 0.f ? 1u : 0u) | (p.y > 0.f ? 2u : 0u) |
                                (p.z > 0.f ? 4u : 0u) | (p.w > 0.f ? 8u : 0u);
            nv |= (unsigned long long)(tn | (pn << 4)) << (8 * s);
        }
        nibw[wv * 2 + g][quad * 8 + rlow] = nv;      // one b64 write per group
    }
    __syncthreads();

    // ---------------- Phase B: build per-column 64-row masks from LDS --------
    const int c   = tid & 31;                        // column within strip
    const int q   = tid >> 5;                        // 64-row chunk (0..15)
    const int h0  = q * 64;
    const int qs  = (c >> 2) * 8;                    // word base for this col's quad
    const int tsh = c & 3;                           // T bit shift within nibble

    unsigned long long tw = 0ull, pw = 0ull;
#pragma unroll
    for (int r = 0; r < 8; ++r) {
        const unsigned long long x  = nibw[q][qs + r];
        const unsigned long long tb = (x >> tsh)       & 0x0101010101010101ULL;
        const unsigned long long pb = (x >> (4 + tsh)) & 0x0101010101010101ULL;
        tw |= tb << r;                               // bit (8s + r) = row h0+8s+r
        pw |= pb << r;
    }

    const int first = tw ? __builtin_ctzll(tw) : -1;
    const int last  = tw ? (63 - __builtin_clzll(tw)) : -1;
    st_first[q][c] = first;
    st_last[q][c]  = last;
    __syncthreads();

    // cross-chunk carries
    int U = BIGD;                                    // dist from row h0-1 up to nearest target
    for (int k = q - 1; k >= 0; --k) {
        const int l2 = st_last[k][c];
        if (l2 >= 0) { U = (h0 - 1) - (k * 64 + l2); break; }
    }
    int nxt_below = BIGD;                            // first target row below this chunk
    for (int k = q + 1; k < 16; ++k) {
        const int fs = st_first[k][c];
        if (fs >= 0) { nxt_below = k * 64 + fs; break; }
    }

    int f   = U;                                     // fwd dist at row h0-1
    int nxt = (first >= 0) ? (h0 + first) : nxt_below;
    unsigned tot = 0u, cnt = 0u;

#pragma unroll 4
    for (int b = 0; b < 64; ++b) {
        const int h = h0 + b;
        const int t = (int)((tw >> b) & 1ull);
        f = t ? 0 : (f + 1);
        if (h > nxt) {                               // passed a target: next set bit >= b
            const unsigned long long m = tw & (~0ull << b);
            nxt = m ? (h0 + __builtin_ctzll(m)) : nxt_below;
        }
        int d = nxt - h;
        d = (f < d) ? f : d;
        d = (d < HH) ? d : HH;                       // cap (no-target columns)
        if (((pw >> b) & 1ull) && d > 0) { tot += (unsigned)d; cnt += 1u; }
    }

    // ---------------- block reduction -> per-block partial slots -------------
    red_f[tid] = bce; red_t[tid] = tot; red_c[tid] = cnt;
    __syncthreads();
    for (int off = NT / 2; off > 0; off >>= 1) {
        if (tid < off) {
            red_f[tid] += red_f[tid + off];
            red_t[tid] += red_t[tid + off];
            red_c[tid] += red_c[tid + off];
        }
        __syncthreads();
    }
    if (tid == 0) {
        bceP[blockIdx.x] = (double)red_f[0];
        totP[blockIdx.x] = red_t[0];
        cntP[blockIdx.x] = red_c[0];
    }
}

// ---------------------------------------------------------------------------
// Final reduce: 1024 partial slots -> scalar loss. No atomics anywhere.
// ---------------------------------------------------------------------------
__global__ __launch_bounds__(512) void dtl_final(const double* __restrict__ bceP,
                                                 const unsigned* __restrict__ totP,
                                                 const unsigned* __restrict__ cntP,
                                                 float* __restrict__ out) {
    __shared__ double             rf[512];
    __shared__ unsigned long long rt[512];
    __shared__ unsigned           rc[512];
    const int t = threadIdx.x;
    rf[t] = bceP[t] + bceP[t + 512];
    rt[t] = (unsigned long long)totP[t] + (unsigned long long)totP[t + 512];
    rc[t] = cntP[t] + cntP[t + 512];
    __syncthreads();
    for (int off = 256; off > 0; off >>= 1) {
        if (t < off) { rf[t] += rf[t + off]; rt[t] += rt[t + off]; rc[t] += rc[t + off]; }
        __syncthreads();
    }
    if (t == 0) {
        const double bce = rf[0] / (double)((size_t)NIMG * HH * WW);
        double border = 0.0;
        if (rt[0] != 0ull) {
            const unsigned cc = (rc[0] > 1u) ? rc[0] : 1u;
            border = sqrt((double)rt[0] / (double)cc);
        }
        out[0] = (float)(bce + border);
    }
}

extern "C" void kernel_launch(void* const* d_in, const int* in_sizes, int n_in,
                              void* d_out, int out_size, void* d_ws, size_t ws_size,
                              hipStream_t stream) {
    const float* pred = (const float*)d_in[0];
    const float* tgt  = (const float*)d_in[1];
    float* out = (float*)d_out;

    double*   bceP = (double*)d_ws;
    unsigned* totP = (unsigned*)((char*)d_ws + 8192);
    unsigned* cntP = totP + NBLK;

    dtl_main<<<NBLK, NT, 0, stream>>>(pred, tgt, bceP, totP, cntP);
    dtl_final<<<1, 512, 0, stream>>>(bceP, totP, cntP, out);
}

// Round 5
// 75.354 us; speedup vs baseline: 3.3957x; 2.0055x over previous
//
#include <hip/hip_runtime.h>
#include <math.h>

#define HH   1024
#define WW   1024
#define NIMG 32
#define NBLK (NIMG * (WW / 32))     // 1024 blocks: (image, 32-col strip)
#define NT   512
#define BIGD (1<<20)

// d_ws layout: double bceP[NBLK]; unsigned totP[NBLK]; unsigned cntP[NBLK]

__global__ __launch_bounds__(NT, 8) void dtl_main(const float* __restrict__ pred,
                                                  const float* __restrict__ tgt,
                                                  double* __restrict__ bceP,
                                                  unsigned* __restrict__ totP,
                                                  unsigned* __restrict__ cntP) {
    // nibw[row>>6][ quad*8 + (row&7) ] : byte s = nibble-pair for row
    // (row>>6)*64 + s*8 + (row&7), cols quad*4..quad*4+3 (T bits0-3, P bits4-7)
    __shared__ unsigned long long nibw[16][64];      // 8 KiB
    __shared__ int st_first[16][32];
    __shared__ int st_last[16][32];
    __shared__ float    red_f[NT];
    __shared__ unsigned red_t[NT];
    __shared__ unsigned red_c[NT];

    const int tid   = threadIdx.x;
    const int lane  = tid & 63;
    const int wv    = tid >> 6;                      // 0..7
    const int n     = blockIdx.x >> 5;               // image
    const int strip = blockIdx.x & 31;               // col base = strip*32

    // ---------------- Phase A: coalesced float4 stream -> BCE + LDS nibbles --
    const int rlow = lane & 7;                       // row offset within octet
    const int quad = lane >> 3;                      // col quad within strip (0..7)
    const size_t f4base = ((size_t)n * HH + (size_t)(wv * 128 + rlow)) * (WW / 4)
                        + (size_t)(strip * 8 + quad);
    const float4* Pp = (const float4*)pred + f4base;
    const float4* Tp = (const float4*)tgt  + f4base;

    float bce = 0.f;
#pragma unroll 1
    for (int g = 0; g < 2; ++g) {                    // two 64-row groups per wave
        unsigned long long nv = 0ull;
#pragma unroll 4
        for (int s = 0; s < 8; ++s) {                // 8 row-octets per group
            const unsigned off = (unsigned)g * 16384u + (unsigned)s * 2048u;
            const float4 p = Pp[off];
            const float4 t = Tp[off];

            bce += fmaxf(p.x, 0.f) - p.x * t.x + __logf(1.f + __expf(-fabsf(p.x)));
            bce += fmaxf(p.y, 0.f) - p.y * t.y + __logf(1.f + __expf(-fabsf(p.y)));
            bce += fmaxf(p.z, 0.f) - p.z * t.z + __logf(1.f + __expf(-fabsf(p.z)));
            bce += fmaxf(p.w, 0.f) - p.w * t.w + __logf(1.f + __expf(-fabsf(p.w)));

            const unsigned tn = (unsigned)t.x | ((unsigned)t.y << 1) |
                                ((unsigned)t.z << 2) | ((unsigned)t.w << 3);
            const unsigned pn = (p.x > 0.f ? 1u : 0u) | (p.y > 0.f ? 2u : 0u) |
                                (p.z > 0.f ? 4u : 0u) | (p.w > 0.f ? 8u : 0u);
            nv |= (unsigned long long)(tn | (pn << 4)) << (8 * s);
        }
        nibw[wv * 2 + g][quad * 8 + rlow] = nv;      // one b64 write per group
    }
    __syncthreads();

    // ---------------- Phase B: per-column 64-row masks from LDS --------------
    const int c   = tid & 31;                        // column within strip
    const int q   = tid >> 5;                        // 64-row chunk (0..15)
    const int h0  = q * 64;
    const int qs  = (c >> 2) * 8;                    // word base for this col's quad
    const int tsh = c & 3;                           // T bit shift within nibble

    unsigned long long tw = 0ull, pw = 0ull;
#pragma unroll
    for (int r = 0; r < 8; ++r) {
        const unsigned long long x  = nibw[q][qs + r];
        const unsigned long long tb = (x >> tsh)       & 0x0101010101010101ULL;
        const unsigned long long pb = (x >> (4 + tsh)) & 0x0101010101010101ULL;
        tw |= tb << r;                               // bit (8s + r) = row h0+8s+r
        pw |= pb << r;
    }

    const int first = tw ? __builtin_ctzll(tw) : -1;
    const int last  = tw ? (63 - __builtin_clzll(tw)) : -1;
    st_first[q][c] = first;
    st_last[q][c]  = last;
    __syncthreads();

    // cross-chunk carries
    int U = BIGD;                                    // dist from row h0-1 up to nearest target
    for (int k = q - 1; k >= 0; --k) {
        const int l2 = st_last[k][c];
        if (l2 >= 0) { U = (h0 - 1) - (k * 64 + l2); break; }
    }
    int nxt_below = BIGD;                            // first target row below this chunk
    for (int k = q + 1; k < 16; ++k) {
        const int fs = st_first[k][c];
        if (fs >= 0) { nxt_below = k * 64 + fs; break; }
    }

    int f   = U;                                     // fwd dist at row h0-1
    int nxt = (first >= 0) ? (h0 + first) : nxt_below;
    unsigned tot = 0u, cnt = 0u;

#pragma unroll 4
    for (int b = 0; b < 64; ++b) {
        const int h = h0 + b;
        const int t = (int)((tw >> b) & 1ull);
        f = t ? 0 : (f + 1);
        if (h > nxt) {                               // passed a target: next set bit >= b
            const unsigned long long m = tw & (~0ull << b);
            nxt = m ? (h0 + __builtin_ctzll(m)) : nxt_below;
        }
        int d = nxt - h;
        d = (f < d) ? f : d;
        d = (d < HH) ? d : HH;                       // cap (no-target columns)
        if (((pw >> b) & 1ull) && d > 0) { tot += (unsigned)d; cnt += 1u; }
    }

    // ---------------- block reduction -> per-block partial slots -------------
    red_f[tid] = bce; red_t[tid] = tot; red_c[tid] = cnt;
    __syncthreads();
    for (int off = NT / 2; off > 0; off >>= 1) {
        if (tid < off) {
            red_f[tid] += red_f[tid + off];
            red_t[tid] += red_t[tid + off];
            red_c[tid] += red_c[tid + off];
        }
        __syncthreads();
    }
    if (tid == 0) {
        bceP[blockIdx.x] = (double)red_f[0];
        totP[blockIdx.x] = red_t[0];
        cntP[blockIdx.x] = red_c[0];
    }
}

// ---------------------------------------------------------------------------
// Final reduce: 1024 partial slots -> scalar loss. No atomics anywhere.
// ---------------------------------------------------------------------------
__global__ __launch_bounds__(512) void dtl_final(const double* __restrict__ bceP,
                                                 const unsigned* __restrict__ totP,
                                                 const unsigned* __restrict__ cntP,
                                                 float* __restrict__ out) {
    __shared__ double             rf[512];
    __shared__ unsigned long long rt[512];
    __shared__ unsigned           rc[512];
    const int t = threadIdx.x;
    rf[t] = bceP[t] + bceP[t + 512];
    rt[t] = (unsigned long long)totP[t] + (unsigned long long)totP[t + 512];
    rc[t] = cntP[t] + cntP[t + 512];
    __syncthreads();
    for (int off = 256; off > 0; off >>= 1) {
        if (t < off) { rf[t] += rf[t + off]; rt[t] += rt[t + off]; rc[t] += rc[t + off]; }
        __syncthreads();
    }
    if (t == 0) {
        const double bce = rf[0] / (double)((size_t)NIMG * HH * WW);
        double border = 0.0;
        if (rt[0] != 0ull) {
            const unsigned cc = (rc[0] > 1u) ? rc[0] : 1u;
            border = sqrt((double)rt[0] / (double)cc);
        }
        out[0] = (float)(bce + border);
    }
}

extern "C" void kernel_launch(void* const* d_in, const int* in_sizes, int n_in,
                              void* d_out, int out_size, void* d_ws, size_t ws_size,
                              hipStream_t stream) {
    const float* pred = (const float*)d_in[0];
    const float* tgt  = (const float*)d_in[1];
    float* out = (float*)d_out;

    double*   bceP = (double*)d_ws;
    unsigned* totP = (unsigned*)((char*)d_ws + 8192);
    unsigned* cntP = totP + NBLK;

    dtl_main<<<NBLK, NT, 0, stream>>>(pred, tgt, bceP, totP, cntP);
    dtl_final<<<1, 512, 0, stream>>>(bceP, totP, cntP, out);
}